// Round 1
// baseline (118.028 us; speedup 1.0000x reference)
//
#include <hip/hip_runtime.h>

// LIF scan: z [B=32, T=1024, H=512] fp32 -> out [32,1024,512] fp32
//   V_t = 0.9*V_{t-1} + z[:,t-1,:] - (V_{t-1} > 1)      (exact fp32 op order)
//   out[:,t,:] = (V_t > 1) ? 1 : 0,  out[:,0,:] = 0
//
// R3 diagnosis: 1 wave/CU alternating load/compute/store phases caps
// in-flight bytes at ~8 KB/CU (need ~9.3 KB *continuously* for 6.3 TB/s;
// measured effective ~1.6 KB/CU -> 1.1 TB/s). The serial V-chain throttles
// load issue because one instruction stream does everything.
//
// R4 fix: producer/consumer decoupling.
//   Block = 320 threads (5 waves): wave 0 = consumer (64 chains = one
//   64-wide h-slice of one batch), waves 1-4 = producers.
//   Producers stream z rows into a double-buffered LDS superchunk
//   (CH=128 timesteps x 256 B = 32 KB) with global_load_lds_dwordx4:
//   each instruction covers 4 t-rows (16 lanes x 16 B per row), 8
//   instructions per producer per superchunk -> 32 KB/CU in flight.
//   Producers s_waitcnt vmcnt(0) then raw s_barrier; consumer computes the
//   previous superchunk from LDS meanwhile (reg-batched ds_reads, 32 at a
//   time, fenced with sched_barrier so the scan chain never waits on HBM).
//   Raw s_barrier (not __syncthreads) so the consumer's in-flight spike
//   stores are NOT drained at each superchunk boundary.

#define LIF_H 512
#define LIF_T 1024
#define CH 128            // timesteps per superchunk
#define NCH 8             // 8*128 = 1024 rows staged; 1023 steps computed
#define NPROD 4           // producer waves
#define NTHREADS (64 * (1 + NPROD))

__global__ __launch_bounds__(NTHREADS, 1) void lif_kernel(const float* __restrict__ z,
                                                          float* __restrict__ out) {
    __shared__ float lds[2][CH * 64];   // 2 x 32 KB

    const int tid  = threadIdx.x;
    const int wave = tid >> 6;
    const int lane = tid & 63;
    const int bid  = blockIdx.x;        // 0..255
    const int b    = bid >> 3;          // batch
    const int h0   = (bid & 7) << 6;    // 64-wide h-slice

    const float* zb = z   + b * (LIF_T * LIF_H) + h0;   // row t = zb + t*512
    float*       ob = out + b * (LIF_T * LIF_H) + h0;

    // ---- prologue: stage superchunk 0; consumer zeroes the t=0 row ----
    if (wave == 0) {
        ob[lane] = 0.0f;
    } else {
        const int p = wave - 1;         // 0..3
#pragma unroll
        for (int j = 0; j < 8; ++j) {
            const int r0 = p * 32 + j * 4;                    // local row base
            const float* g = zb + (r0 + (lane >> 4)) * LIF_H + (lane & 15) * 4;
            __builtin_amdgcn_global_load_lds(
                (__attribute__((address_space(1))) void*)g,
                (__attribute__((address_space(3))) void*)&lds[0][r0 * 64],
                16, 0, 0);
        }
        asm volatile("s_waitcnt vmcnt(0)" ::: "memory");
    }
    asm volatile("" ::: "memory");
    __builtin_amdgcn_s_barrier();
    asm volatile("" ::: "memory");

    float V = 0.0f;

    for (int c = 0; c < NCH; ++c) {
        const int cur = c & 1;

        if (wave > 0) {
            // ---- producers: stage superchunk c+1 into the other buffer ----
            if (c + 1 < NCH) {
                const int p = wave - 1;
#pragma unroll
                for (int j = 0; j < 8; ++j) {
                    const int r0 = p * 32 + j * 4;
                    const float* g = zb + ((c + 1) * CH + r0 + (lane >> 4)) * LIF_H
                                        + (lane & 15) * 4;
                    __builtin_amdgcn_global_load_lds(
                        (__attribute__((address_space(1))) void*)g,
                        (__attribute__((address_space(3))) void*)&lds[cur ^ 1][r0 * 64],
                        16, 0, 0);
                }
                asm volatile("s_waitcnt vmcnt(0)" ::: "memory");
            }
        } else {
            // ---- consumer: run the scan over superchunk c from LDS ----
            const float* lb = &lds[cur][0];
            const bool lastc = (c == NCH - 1);   // 127 steps instead of 128
#pragma unroll 1
            for (int sub = 0; sub < 4; ++sub) {
                float rb[32];
#pragma unroll
                for (int i = 0; i < 32; ++i)
                    rb[i] = lb[(sub * 32 + i) * 64 + lane];
                __builtin_amdgcn_sched_barrier(0);

                const int s0 = c * CH + sub * 32;
                if (!lastc || sub < 3) {
#pragma unroll
                    for (int i = 0; i < 32; ++i) {
                        const float v0 = __fadd_rn(__fmul_rn(0.9f, V), rb[i]);
                        const float Vn = (V > 1.0f) ? __fsub_rn(v0, 1.0f) : v0;
                        ob[(s0 + i + 1) * LIF_H + lane] = (Vn > 1.0f) ? 1.0f : 0.0f;
                        V = Vn;
                    }
                } else {
#pragma unroll
                    for (int i = 0; i < 31; ++i) {   // tail: steps 992..1022
                        const float v0 = __fadd_rn(__fmul_rn(0.9f, V), rb[i]);
                        const float Vn = (V > 1.0f) ? __fsub_rn(v0, 1.0f) : v0;
                        ob[(s0 + i + 1) * LIF_H + lane] = (Vn > 1.0f) ? 1.0f : 0.0f;
                        V = Vn;
                    }
                }
                __builtin_amdgcn_sched_barrier(0);
            }
        }

        asm volatile("" ::: "memory");
        __builtin_amdgcn_s_barrier();
        asm volatile("" ::: "memory");
    }
}

extern "C" void kernel_launch(void* const* d_in, const int* in_sizes, int n_in,
                              void* d_out, int out_size, void* d_ws, size_t ws_size,
                              hipStream_t stream) {
    const float* z = (const float*)d_in[0];
    float* out = (float*)d_out;
    hipLaunchKernelGGL(lif_kernel, dim3(256), dim3(NTHREADS), 0, stream, z, out);
}

// Round 2
// 113.430 us; speedup vs baseline: 1.0405x; 1.0405x over previous
//
#include <hip/hip_runtime.h>

// LIF scan: z [B=32, T=1024, H=512] fp32 -> out [32,1024,512] fp32
//   V_t = 0.9*V_{t-1} + z[:,t-1,:] - (V_{t-1} > 1)      (exact fp32 op order)
//   out[:,t,:] = (V_t > 1) ? 1 : 0,  out[:,0,:] = 0
//
// R4 lesson: producer/consumer with double buffer + vmcnt(0) per phase =
//   42.7 us (2.4 TB/s). Full HBM latency exposed every phase: chunk c+1 is
//   issued AND drained inside phase c. No prefetch distance.
// R5 fix: triple buffer + counted vmcnt (T3/T4 pattern).
//   Phase c: producers issue chunk c+2 (8 x global_load_lds_dwordx4 each),
//   then s_waitcnt vmcnt(8) -> drains chunk c+1 (issued one full phase ago,
//   ~3 us in flight -> ~zero exposed stall); chunk c+2's loads cross the
//   raw s_barrier still in flight. Consumer computes chunk c meanwhile.
//   Also: V-chain shortened to 3 dependent ops (mul->add->sub; reset r is
//   the previous spike value, computed off-chain; u - 0.0f == u bit-exact),
//   and consumer LDS->reg batches are double-buffered (rbA/rbB) so ds_read
//   latency hides under the previous batch's serial chain.

#define LIF_H 512
#define LIF_T 1024
#define CH 128            // timesteps per superchunk (32 KB per buffer)
#define NCH 8             // 8*128 = 1024 rows staged; 1023 steps computed
#define NPROD 4
#define NTHREADS (64 * (1 + NPROD))

#define GLDS(gptr, lptr)                                                     \
    __builtin_amdgcn_global_load_lds(                                        \
        (const __attribute__((address_space(1))) void*)(gptr),               \
        (__attribute__((address_space(3))) void*)(lptr), 16, 0, 0)

__global__ __launch_bounds__(NTHREADS, 1) void lif_kernel(const float* __restrict__ z,
                                                          float* __restrict__ out) {
    extern __shared__ float lds[];      // 3 x CH x 64 floats = 96 KB

    const int tid  = threadIdx.x;
    const int wave = tid >> 6;
    const int lane = tid & 63;
    const int bid  = blockIdx.x;        // 0..255
    const int b    = bid >> 3;          // batch
    const int h0   = (bid & 7) << 6;    // 64-wide h-slice

    const float* zb = z   + b * (LIF_T * LIF_H) + h0;   // row t = zb + t*512
    float*       ob = out + b * (LIF_T * LIF_H) + h0;

    // ---- prologue: stage chunks 0,1; consumer zeroes the t=0 row ----
    if (wave == 0) {
        ob[lane] = 0.0f;
    } else {
        const int p = wave - 1;         // 0..3
#pragma unroll
        for (int j = 0; j < 8; ++j) {
            const int r0 = p * 32 + j * 4;
            GLDS(zb + (r0 + (lane >> 4)) * LIF_H + (lane & 15) * 4,
                 &lds[0 * (CH * 64) + r0 * 64]);
        }
#pragma unroll
        for (int j = 0; j < 8; ++j) {
            const int r0 = p * 32 + j * 4;
            GLDS(zb + (CH + r0 + (lane >> 4)) * LIF_H + (lane & 15) * 4,
                 &lds[1 * (CH * 64) + r0 * 64]);
        }
        __builtin_amdgcn_sched_barrier(0);
        asm volatile("s_waitcnt vmcnt(8)" ::: "memory");   // chunk 0 landed
    }
    __builtin_amdgcn_s_barrier();

    float V = 0.0f;
    float r = 0.0f;                     // reset = previous spike (V0=0 -> 0)
    int cbuf = 0;                       // buffer holding chunk c

#define LDRB(rb, sub)                                                        \
    _Pragma("unroll")                                                        \
    for (int i = 0; i < 32; ++i) rb[i] = lb[((sub) * 32 + i) * 64 + lane];

#define CHAIN(rb, s0, N)                                                     \
    _Pragma("unroll")                                                        \
    for (int i = 0; i < (N); ++i) {                                          \
        const float u  = __fadd_rn(__fmul_rn(0.9f, V), rb[i]);               \
        const float Vn = __fsub_rn(u, r);                                    \
        const float sp = (Vn > 1.0f) ? 1.0f : 0.0f;                          \
        ob[((s0) + i + 1) * LIF_H + lane] = sp;                              \
        r = sp;                                                              \
        V = Vn;                                                              \
    }

#pragma unroll 1
    for (int c = 0; c < NCH; ++c) {
        if (wave > 0) {
            // ---- producers: issue chunk c+2; drain chunk c+1 only ----
            if (c + 2 < NCH) {
                const int p = wave - 1;
                int wbuf = cbuf + 2; if (wbuf >= 3) wbuf -= 3;
                float* dst = &lds[wbuf * (CH * 64)];
                const float* src = zb + (c + 2) * CH * LIF_H;
#pragma unroll
                for (int j = 0; j < 8; ++j) {
                    const int r0 = p * 32 + j * 4;
                    GLDS(src + (r0 + (lane >> 4)) * LIF_H + (lane & 15) * 4,
                         &dst[r0 * 64]);
                }
                __builtin_amdgcn_sched_barrier(0);
                asm volatile("s_waitcnt vmcnt(8)" ::: "memory");  // c+1 landed
            } else if (c + 1 < NCH) {
                asm volatile("s_waitcnt vmcnt(0)" ::: "memory");  // chunk 7 landed
            }
        } else {
            // ---- consumer: scan chunk c from LDS (reg double-buffered) ----
            const float* lb = &lds[cbuf * (CH * 64)];
            const int s0 = c * CH;
            float rbA[32], rbB[32];
            LDRB(rbA, 0);
            LDRB(rbB, 1);
            __builtin_amdgcn_sched_barrier(0);
            CHAIN(rbA, s0 + 0, 32);
            LDRB(rbA, 2);
            __builtin_amdgcn_sched_barrier(0);
            CHAIN(rbB, s0 + 32, 32);
            LDRB(rbB, 3);
            __builtin_amdgcn_sched_barrier(0);
            CHAIN(rbA, s0 + 64, 32);
            __builtin_amdgcn_sched_barrier(0);
            if (c < NCH - 1) {
                CHAIN(rbB, s0 + 96, 32);
            } else {
                CHAIN(rbB, s0 + 96, 31);   // steps 992..1022
            }
        }

        __builtin_amdgcn_s_barrier();
        cbuf = (cbuf == 2) ? 0 : cbuf + 1;
    }
}

extern "C" void kernel_launch(void* const* d_in, const int* in_sizes, int n_in,
                              void* d_out, int out_size, void* d_ws, size_t ws_size,
                              hipStream_t stream) {
    const float* z = (const float*)d_in[0];
    float* out = (float*)d_out;
    hipLaunchKernelGGL(lif_kernel, dim3(256), dim3(NTHREADS),
                       3 * CH * 64 * sizeof(float), stream, z, out);
}